// Round 1
// baseline (301.532 us; speedup 1.0000x reference)
//
#include <hip/hip_runtime.h>
#include <stdint.h>

// ---------------------------------------------------------------------------
// patch-MLP: per-patch 2-layer MLP (GELU exact) + residual, fp32 in/out.
// Strategy: split-bf16 (hi/lo) 3-term MFMA GEMM pairs, m97-style 128x128 tile.
//   h = gelu(x @ W1^T + b1); o = h @ W2^T + b2 + x
// B=32 N=128 P=8 D=512  -> per patch GEMM: M=4096, N=512, K=512
// ---------------------------------------------------------------------------

typedef unsigned short u16;
typedef __attribute__((ext_vector_type(8))) short bf16x8;
typedef __attribute__((ext_vector_type(4))) float f32x4;

#define AS1 __attribute__((address_space(1)))
#define AS3 __attribute__((address_space(3)))

#define MTOT 4096      // B*N rows
#define PATCHES 8
#define DDIM 512
#define ROWSTRIDE 4096 // P*D

__device__ __forceinline__ void glds16(const void* g, void* l) {
  __builtin_amdgcn_global_load_lds((const AS1 uint32_t*)g, (AS3 uint32_t*)l, 16, 0, 0);
}

__device__ __forceinline__ u16 bf16_rne(float v) {
  union { float f; uint32_t u; } c; c.f = v;
  uint32_t u = c.u + 0x7FFFu + ((c.u >> 16) & 1u);
  return (u16)(u >> 16);
}
__device__ __forceinline__ float bf16_to_f(u16 h) {
  union { uint32_t u; float f; } c; c.u = ((uint32_t)h) << 16;
  return c.f;
}
__device__ __forceinline__ void split2(float v, u16& hi, u16& lo) {
  hi = bf16_rne(v);
  float r = v - bf16_to_f(hi);
  lo = bf16_rne(r);
}

// ---------------------------------------------------------------------------
// fp32 -> (hi, lo) bf16 split, vectorized float4 / ushort4
// ---------------------------------------------------------------------------
__global__ void split_kernel(const float* __restrict__ in,
                             u16* __restrict__ hi, u16* __restrict__ lo, int n) {
  int i = (blockIdx.x * blockDim.x + threadIdx.x) * 4;
  int stride = gridDim.x * blockDim.x * 4;
  for (; i < n; i += stride) {
    float4 v = *reinterpret_cast<const float4*>(in + i);
    ushort4 h, l;
    split2(v.x, h.x, l.x);
    split2(v.y, h.y, l.y);
    split2(v.z, h.z, l.z);
    split2(v.w, h.w, l.w);
    *reinterpret_cast<ushort4*>(hi + i) = h;
    *reinterpret_cast<ushort4*>(lo + i) = l;
  }
}

// ---------------------------------------------------------------------------
// Split-bf16 GEMM:  C[m, p, n] = sum_d A[m, p, d] * W[p, n, d]  (+ epilogue)
// A arrays laid out [m][p][d] (x / h layout), W arrays [p][n][d].
// EPI==1: gelu(acc + bias) -> split-store to OutHi/OutLo (h for layer 2)
// EPI==2: acc + bias + resid -> fp32 OutF
// Block: 256 thr = 4 waves (2x2), tile 128x128, BK=32, K-iters = 16.
// ---------------------------------------------------------------------------
template <int EPI>
__global__ __launch_bounds__(256) void gemm_split(
    const u16* __restrict__ Ahi, const u16* __restrict__ Alo,
    const u16* __restrict__ Bhi, const u16* __restrict__ Blo,
    const float* __restrict__ bias,   // [P][512]
    const float* __restrict__ resid,  // [m][p][d]  (EPI==2)
    u16* __restrict__ OutHi, u16* __restrict__ OutLo,  // EPI==1
    float* __restrict__ OutF)         // EPI==2
{
  // XCD-aware bijective swizzle (1024 blocks % 8 == 0): each XCD owns 1 patch
  const int nwg = gridDim.x;
  const int bid = blockIdx.x;
  const int swz = (bid & 7) * (nwg >> 3) + (bid >> 3);
  const int nt = swz & 3;          // 4 col tiles of 128 over N=512
  const int mt = (swz >> 2) & 31;  // 32 row tiles of 128 over M=4096
  const int p  = swz >> 7;         // 8 patches

  __shared__ __attribute__((aligned(16))) u16 lsAhi[128 * 32];
  __shared__ __attribute__((aligned(16))) u16 lsAlo[128 * 32];
  __shared__ __attribute__((aligned(16))) u16 lsBhi[128 * 32];
  __shared__ __attribute__((aligned(16))) u16 lsBlo[128 * 32];

  const int tid = threadIdx.x;
  const int lane = tid & 63;
  const int wv = tid >> 6;
  const int wr = wv >> 1;          // wave row (0..1), 64 rows each
  const int wc = wv & 1;           // wave col (0..1), 64 cols each
  const int fr = lane & 15;        // fragment row/col within 16
  const int fk = (lane >> 4) * 8;  // fragment k offset within 32

  // staging: per thread 8 contiguous bf16 (16B); 2 chunks per array
  const int e0 = tid * 8;          // element offset in [128][32] tile
  const int r0 = e0 >> 5;          // row 0..63
  const int c0 = e0 & 31;
  const size_t aBase  = (size_t)(mt * 128 + r0) * ROWSTRIDE + (size_t)p * DDIM + c0;
  const size_t aBase1 = aBase + (size_t)64 * ROWSTRIDE;
  const size_t bBase  = (size_t)p * (DDIM * DDIM) + (size_t)(nt * 128 + r0) * DDIM + c0;
  const size_t bBase1 = bBase + (size_t)64 * DDIM;

  f32x4 acc[4][4] = {};

  for (int kt = 0; kt < 16; ++kt) {
    const int ko = kt * 32;
    glds16(Ahi + aBase  + ko, &lsAhi[e0]);
    glds16(Ahi + aBase1 + ko, &lsAhi[e0 + 2048]);
    glds16(Alo + aBase  + ko, &lsAlo[e0]);
    glds16(Alo + aBase1 + ko, &lsAlo[e0 + 2048]);
    glds16(Bhi + bBase  + ko, &lsBhi[e0]);
    glds16(Bhi + bBase1 + ko, &lsBhi[e0 + 2048]);
    glds16(Blo + bBase  + ko, &lsBlo[e0]);
    glds16(Blo + bBase1 + ko, &lsBlo[e0 + 2048]);
    __syncthreads();  // drains vmcnt before barrier -> staged data visible

    bf16x8 ah[4], al[4], bh[4], bl[4];
#pragma unroll
    for (int i = 0; i < 4; ++i) {
      const int ra = (wr * 64 + i * 16 + fr) * 32 + fk;
      const int rb = (wc * 64 + i * 16 + fr) * 32 + fk;
      ah[i] = *(const bf16x8*)&lsAhi[ra];
      al[i] = *(const bf16x8*)&lsAlo[ra];
      bh[i] = *(const bf16x8*)&lsBhi[rb];
      bl[i] = *(const bf16x8*)&lsBlo[rb];
    }
#pragma unroll
    for (int i = 0; i < 4; ++i) {
#pragma unroll
      for (int j = 0; j < 4; ++j) {
        acc[i][j] = __builtin_amdgcn_mfma_f32_16x16x32_bf16(ah[i], bh[j], acc[i][j], 0, 0, 0);
        acc[i][j] = __builtin_amdgcn_mfma_f32_16x16x32_bf16(al[i], bh[j], acc[i][j], 0, 0, 0);
        acc[i][j] = __builtin_amdgcn_mfma_f32_16x16x32_bf16(ah[i], bl[j], acc[i][j], 0, 0, 0);
      }
    }
    __syncthreads();  // protect LDS before next stage
  }

  // epilogue: C/D layout col = lane&15, row = (lane>>4)*4 + r   [m89-verified]
  const int rquad = (lane >> 4) * 4;
#pragma unroll
  for (int j = 0; j < 4; ++j) {
    const int col = nt * 128 + wc * 64 + j * 16 + fr;
    const float bj = bias[p * DDIM + col];
#pragma unroll
    for (int i = 0; i < 4; ++i) {
      const int row = mt * 128 + wr * 64 + i * 16 + rquad;
#pragma unroll
      for (int r = 0; r < 4; ++r) {
        const size_t idx = (size_t)(row + r) * ROWSTRIDE + (size_t)p * DDIM + col;
        float o = acc[i][j][r] + bj;
        if constexpr (EPI == 1) {
          o = 0.5f * o * (1.0f + erff(o * 0.70710678118654752f));  // exact GELU
          u16 h_, l_;
          split2(o, h_, l_);
          OutHi[idx] = h_;
          OutLo[idx] = l_;
        } else {
          OutF[idx] = o + resid[idx];
        }
      }
    }
  }
}

// ---------------------------------------------------------------------------
extern "C" void kernel_launch(void* const* d_in, const int* in_sizes, int n_in,
                              void* d_out, int out_size, void* d_ws, size_t ws_size,
                              hipStream_t stream) {
  const float* x  = (const float*)d_in[0];
  const float* W1 = (const float*)d_in[1];
  const float* b1 = (const float*)d_in[2];
  const float* W2 = (const float*)d_in[3];
  const float* b2 = (const float*)d_in[4];
  float* out = (float*)d_out;

  const int NX = MTOT * PATCHES * DDIM;   // 16,777,216
  const int NW = PATCHES * DDIM * DDIM;   // 2,097,152

  u16* ws   = (u16*)d_ws;
  u16* xhi  = ws;              // NX
  u16* xlo  = xhi + NX;
  u16* w1hi = xlo + NX;        // NW
  u16* w1lo = w1hi + NW;
  u16* w2hi = w1lo + NW;
  u16* w2lo = w2hi + NW;
  u16* hhi  = w2lo + NW;       // NX
  u16* hlo  = hhi + NX;        // total 151 MB

  split_kernel<<<2048, 256, 0, stream>>>(x,  xhi,  xlo,  NX);
  split_kernel<<<512,  256, 0, stream>>>(W1, w1hi, w1lo, NW);
  split_kernel<<<512,  256, 0, stream>>>(W2, w2hi, w2lo, NW);

  gemm_split<1><<<1024, 256, 0, stream>>>(xhi, xlo, w1hi, w1lo, b1, nullptr,
                                          hhi, hlo, nullptr);
  gemm_split<2><<<1024, 256, 0, stream>>>(hhi, hlo, w2hi, w2lo, b2, x,
                                          nullptr, nullptr, out);
}

// Round 2
// 297.380 us; speedup vs baseline: 1.0140x; 1.0140x over previous
//
#include <hip/hip_runtime.h>
#include <stdint.h>

// ---------------------------------------------------------------------------
// patch-MLP: per-patch 2-layer MLP (GELU exact) + residual, fp32 in/out.
// Split-bf16 (hi/lo) 3-term MFMA GEMM, 256x256-tile 8-wave phase-split
// schedule (T3+T4-lite) with T2 LDS XOR swizzle and T5 setprio.
//   h = gelu(x @ W1^T + b1); o = h @ W2^T + b2 + x
// B=32 N=128 P=8 D=512  -> per patch GEMM: M=4096, N=512, K=512
// ---------------------------------------------------------------------------

typedef unsigned short u16;
typedef __attribute__((ext_vector_type(8))) short bf16x8;
typedef __attribute__((ext_vector_type(4))) float f32x4;

#define AS1 __attribute__((address_space(1)))
#define AS3 __attribute__((address_space(3)))

#define MTOT 4096      // B*N rows
#define PATCHES 8
#define DDIM 512
#define ROWSTRIDE 4096 // P*D

__device__ __forceinline__ void glds16(const void* g, void* l) {
  __builtin_amdgcn_global_load_lds((const AS1 uint32_t*)g, (AS3 uint32_t*)l, 16, 0, 0);
}

__device__ __forceinline__ u16 bf16_rne(float v) {
  union { float f; uint32_t u; } c; c.f = v;
  uint32_t u = c.u + 0x7FFFu + ((c.u >> 16) & 1u);
  return (u16)(u >> 16);
}
__device__ __forceinline__ float bf16_to_f(u16 h) {
  union { uint32_t u; float f; } c; c.u = ((uint32_t)h) << 16;
  return c.f;
}
__device__ __forceinline__ void split2(float v, u16& hi, u16& lo) {
  hi = bf16_rne(v);
  float r = v - bf16_to_f(hi);
  lo = bf16_rne(r);
}

// ---------------------------------------------------------------------------
// fused fp32 -> (hi, lo) bf16 split for x, W1, W2 in one launch
// ---------------------------------------------------------------------------
__global__ void split3_kernel(const float* __restrict__ x,  u16* xhi,  u16* xlo,  int nx,
                              const float* __restrict__ w1, u16* w1hi, u16* w1lo,
                              const float* __restrict__ w2, u16* w2hi, u16* w2lo, int nw) {
  const int total4 = (nx + 2 * nw) >> 2;
  for (int i4 = blockIdx.x * blockDim.x + threadIdx.x; i4 < total4;
       i4 += gridDim.x * blockDim.x) {
    int i = i4 << 2;
    const float* src; u16* h; u16* l; int off;
    if (i < nx)           { src = x;  h = xhi;  l = xlo;  off = i; }
    else if (i < nx + nw) { src = w1; h = w1hi; l = w1lo; off = i - nx; }
    else                  { src = w2; h = w2hi; l = w2lo; off = i - nx - nw; }
    float4 v = *reinterpret_cast<const float4*>(src + off);
    ushort4 hh, ll;
    split2(v.x, hh.x, ll.x);
    split2(v.y, hh.y, ll.y);
    split2(v.z, hh.z, ll.z);
    split2(v.w, hh.w, ll.w);
    *reinterpret_cast<ushort4*>(h + off) = hh;
    *reinterpret_cast<ushort4*>(l + off) = ll;
  }
}

// ---------------------------------------------------------------------------
// Split-bf16 GEMM, phase-split schedule.
//   C[m, p, n] = sum_d A[m, p, d] * W[p, n, d]  (+ epilogue)
// A planes laid out [m][p][d] (x / h layout), W planes [p][n][d].
// Block: 512 thr = 8 waves (2Mx4N), tile 256x256, BK=32, 16 K-tiles.
// LDS: 2 buf x 4 planes ([256][32] bf16, XOR-swizzled image) = 128 KiB.
// Swizzle: 16B-chunk' = chunk ^ ((row>>1)&3)  (involution; rows 0..7 ->
// 8 distinct bank slots, 2 lanes/bank = free).
// EPI==1: gelu(acc+bias) -> split-store OutHi/OutLo.  EPI==2: +bias+resid.
// ---------------------------------------------------------------------------
template <int EPI>
__global__ __launch_bounds__(512, 2) void gemm_split8(
    const u16* __restrict__ Ahi, const u16* __restrict__ Alo,
    const u16* __restrict__ Bhi, const u16* __restrict__ Blo,
    const float* __restrict__ bias,   // [P][512]
    const float* __restrict__ resid,  // [m][p][d]  (EPI==2)
    u16* __restrict__ OutHi, u16* __restrict__ OutLo,  // EPI==1
    float* __restrict__ OutF)         // EPI==2
{
  // XCD-aware bijective swizzle (256 blocks % 8 == 0): each XCD owns 1 patch
  const int nwg = gridDim.x;                      // 256
  const int bid = blockIdx.x;
  const int swz = (bid & 7) * (nwg >> 3) + (bid >> 3);
  const int nt = swz & 1;          // 2 col tiles of 256 over N=512
  const int mt = (swz >> 1) & 15;  // 16 row tiles of 256 over M=4096
  const int p  = swz >> 5;         // 8 patches

  // planes: 0=Ahi 1=Alo 2=Bhi 3=Blo ; [256 rows][32 cols] bf16 each (16 KiB)
  __shared__ __attribute__((aligned(16))) u16 sm[2][4][256 * 32];

  const int t    = threadIdx.x;
  const int lane = t & 63;
  const int wv   = t >> 6;
  const int wr   = wv >> 2;        // wave row 0..1 -> m base wr*128
  const int wc   = wv & 3;         // wave col 0..3 -> n base wc*64
  const int fr   = lane & 15;
  const int cS   = (lane >> 4) ^ ((fr >> 1) & 3);   // swizzled 16B chunk (reads)

  // staging: thread t owns chunks u0=t, u1=t+512 of each plane (1024 chunks)
  const int sr0 = t >> 2;                 // row 0..127 (chunk u1 -> row+128)
  const int sc  = t & 3;
  const int scS = sc ^ ((sr0 >> 1) & 3);  // s(r+128)==s(r), so same for both
  const int se0 = t * 8;                  // lds elem offset, chunk u0
  const int se1 = se0 + 4096;             // chunk u1

  const size_t aG0 = (size_t)(mt * 256 + sr0)       * ROWSTRIDE + (size_t)p * DDIM + scS * 8;
  const size_t aG1 = (size_t)(mt * 256 + sr0 + 128) * ROWSTRIDE + (size_t)p * DDIM + scS * 8;
  const size_t bG0 = ((size_t)p * DDIM + nt * 256 + sr0)       * DDIM + scS * 8;
  const size_t bG1 = ((size_t)p * DDIM + nt * 256 + sr0 + 128) * DDIM + scS * 8;

  f32x4 acc[8][4] = {};

  // prologue: stage K-tile 0 into buf 0, full drain
  glds16(Ahi + aG0, &sm[0][0][se0]); glds16(Ahi + aG1, &sm[0][0][se1]);
  glds16(Alo + aG0, &sm[0][1][se0]); glds16(Alo + aG1, &sm[0][1][se1]);
  glds16(Bhi + bG0, &sm[0][2][se0]); glds16(Bhi + bG1, &sm[0][2][se1]);
  glds16(Blo + bG0, &sm[0][3][se0]); glds16(Blo + bG1, &sm[0][3][se1]);
  asm volatile("s_waitcnt vmcnt(0)" ::: "memory");
  __builtin_amdgcn_s_barrier();

#define DS_A(pl, m) (*(const bf16x8*)&sm[cur][pl][(wr * 128 + (m) * 16 + fr) * 32 + cS * 8])
#define DS_B(pl, n) (*(const bf16x8*)&sm[cur][pl][(wc * 64  + (n) * 16 + fr) * 32 + cS * 8])
#define MFMA3(m, a_h, a_l)                                                            \
  _Pragma("unroll")                                                                   \
  for (int n = 0; n < 4; ++n) {                                                       \
    acc[m][n] = __builtin_amdgcn_mfma_f32_16x16x32_bf16(a_h, bh[n], acc[m][n], 0,0,0);\
    acc[m][n] = __builtin_amdgcn_mfma_f32_16x16x32_bf16(a_l, bh[n], acc[m][n], 0,0,0);\
    acc[m][n] = __builtin_amdgcn_mfma_f32_16x16x32_bf16(a_h, bl[n], acc[m][n], 0,0,0);\
  }

  for (int kt = 0; kt < 16; ++kt) {
    const int cur = kt & 1, nxt = cur ^ 1;
    const bool stage = (kt != 15);
    const size_t ko = (size_t)(kt + 1) * 32;   // next K-tile global offset

    bf16x8 bh[4], bl[4];

    // ---- phase 0: all B frags + A m0,m1 ; stage next Ahi ----
    {
#pragma unroll
      for (int n = 0; n < 4; ++n) { bh[n] = DS_B(2, n); bl[n] = DS_B(3, n); }
      bf16x8 a0h = DS_A(0, 0), a1h = DS_A(0, 1);
      bf16x8 a0l = DS_A(1, 0), a1l = DS_A(1, 1);
      if (stage) { glds16(Ahi + aG0 + ko, &sm[nxt][0][se0]);
                   glds16(Ahi + aG1 + ko, &sm[nxt][0][se1]); }
      __builtin_amdgcn_s_barrier();
      asm volatile("s_waitcnt lgkmcnt(0)" ::: "memory");
      __builtin_amdgcn_s_setprio(1);
      MFMA3(0, a0h, a0l)
      MFMA3(1, a1h, a1l)
      __builtin_amdgcn_s_setprio(0);
      __builtin_amdgcn_s_barrier();
    }
    // ---- phase 1: A m2,m3 ; stage next Alo ----
    {
      bf16x8 a0h = DS_A(0, 2), a1h = DS_A(0, 3);
      bf16x8 a0l = DS_A(1, 2), a1l = DS_A(1, 3);
      if (stage) { glds16(Alo + aG0 + ko, &sm[nxt][1][se0]);
                   glds16(Alo + aG1 + ko, &sm[nxt][1][se1]); }
      __builtin_amdgcn_s_barrier();
      asm volatile("s_waitcnt lgkmcnt(0)" ::: "memory");
      __builtin_amdgcn_s_setprio(1);
      MFMA3(2, a0h, a0l)
      MFMA3(3, a1h, a1l)
      __builtin_amdgcn_s_setprio(0);
      __builtin_amdgcn_s_barrier();
    }
    // ---- phase 2: A m4,m5 ; stage next Bhi ----
    {
      bf16x8 a0h = DS_A(0, 4), a1h = DS_A(0, 5);
      bf16x8 a0l = DS_A(1, 4), a1l = DS_A(1, 5);
      if (stage) { glds16(Bhi + bG0 + ko, &sm[nxt][2][se0]);
                   glds16(Bhi + bG1 + ko, &sm[nxt][2][se1]); }
      __builtin_amdgcn_s_barrier();
      asm volatile("s_waitcnt lgkmcnt(0)" ::: "memory");
      __builtin_amdgcn_s_setprio(1);
      MFMA3(4, a0h, a0l)
      MFMA3(5, a1h, a1l)
      __builtin_amdgcn_s_setprio(0);
      __builtin_amdgcn_s_barrier();
    }
    // ---- phase 3: A m6,m7 ; stage next Blo ; tile-end vmcnt drain ----
    {
      bf16x8 a0h = DS_A(0, 6), a1h = DS_A(0, 7);
      bf16x8 a0l = DS_A(1, 6), a1l = DS_A(1, 7);
      if (stage) { glds16(Blo + bG0 + ko, &sm[nxt][3][se0]);
                   glds16(Blo + bG1 + ko, &sm[nxt][3][se1]); }
      __builtin_amdgcn_s_barrier();
      asm volatile("s_waitcnt lgkmcnt(0)" ::: "memory");
      __builtin_amdgcn_s_setprio(1);
      MFMA3(6, a0h, a0l)
      MFMA3(7, a1h, a1l)
      __builtin_amdgcn_s_setprio(0);
      // all 8 glds for the next tile must land before any wave reads buf[nxt]
      asm volatile("s_waitcnt vmcnt(0)" ::: "memory");
      __builtin_amdgcn_s_barrier();
    }
  }
#undef DS_A
#undef DS_B
#undef MFMA3

  // epilogue: C/D layout col = lane&15, row = (lane>>4)*4 + r   [m89-verified]
  const int rquad = (lane >> 4) * 4;
#pragma unroll
  for (int j = 0; j < 4; ++j) {
    const int col = nt * 256 + wc * 64 + j * 16 + fr;
    const float bj = bias[p * DDIM + col];
#pragma unroll
    for (int i = 0; i < 8; ++i) {
      const int row = mt * 256 + wr * 128 + i * 16 + rquad;
#pragma unroll
      for (int r = 0; r < 4; ++r) {
        const size_t idx = (size_t)(row + r) * ROWSTRIDE + (size_t)p * DDIM + col;
        float o = acc[i][j][r] + bj;
        if constexpr (EPI == 1) {
          o = 0.5f * o * (1.0f + erff(o * 0.70710678118654752f));  // exact GELU
          u16 h_, l_;
          split2(o, h_, l_);
          OutHi[idx] = h_;
          OutLo[idx] = l_;
        } else {
          OutF[idx] = o + resid[idx];
        }
      }
    }
  }
}

// ---------------------------------------------------------------------------
extern "C" void kernel_launch(void* const* d_in, const int* in_sizes, int n_in,
                              void* d_out, int out_size, void* d_ws, size_t ws_size,
                              hipStream_t stream) {
  const float* x  = (const float*)d_in[0];
  const float* W1 = (const float*)d_in[1];
  const float* b1 = (const float*)d_in[2];
  const float* W2 = (const float*)d_in[3];
  const float* b2 = (const float*)d_in[4];
  float* out = (float*)d_out;

  const int NX = MTOT * PATCHES * DDIM;   // 16,777,216
  const int NW = PATCHES * DDIM * DDIM;   // 2,097,152

  u16* ws   = (u16*)d_ws;
  u16* xhi  = ws;              // NX
  u16* xlo  = xhi + NX;
  u16* w1hi = xlo + NX;        // NW
  u16* w1lo = w1hi + NW;
  u16* w2hi = w1lo + NW;
  u16* w2lo = w2hi + NW;
  u16* hhi  = w2lo + NW;       // NX
  u16* hlo  = hhi + NX;        // total 151 MB

  split3_kernel<<<2048, 256, 0, stream>>>(x, xhi, xlo, NX,
                                          W1, w1hi, w1lo,
                                          W2, w2hi, w2lo, NW);

  gemm_split8<1><<<256, 512, 0, stream>>>(xhi, xlo, w1hi, w1lo, b1, nullptr,
                                          hhi, hlo, nullptr);
  gemm_split8<2><<<256, 512, 0, stream>>>(hhi, hlo, w2hi, w2lo, b2, x,
                                          nullptr, nullptr, out);
}

// Round 6
// 261.426 us; speedup vs baseline: 1.1534x; 1.1375x over previous
//
#include <hip/hip_runtime.h>
#include <stdint.h>

// ---------------------------------------------------------------------------
// patch-MLP: per-patch 2-layer MLP (GELU exact) + residual, fp32 in/out.
//   h = gelu(x @ W1^T + b1); o = h @ W2^T + b2 + x
// B=32 N=128 P=8 D=512  -> per patch GEMM: M=4096, N=512, K=512
// Split-bf16 (hi/lo) 3-term MFMA GEMM. 256x256 tile, 8 waves, BK=32.
// Term-phased schedule (A: ah*bh, B: ah*bl, C: al*bh) with COUNTED vmcnt
// (T4): every plane prefetched 3 phases before its first read; no vmcnt(0)
// in the steady loop. gemm1 splits fp32 x in-kernel (no x-split kernel).
// ---------------------------------------------------------------------------

typedef unsigned short u16;
typedef __attribute__((ext_vector_type(8))) short bf16x8;
typedef __attribute__((ext_vector_type(4))) float f32x4;

#define AS1 __attribute__((address_space(1)))
#define AS3 __attribute__((address_space(3)))

#define MTOT 4096      // B*N rows
#define PATCHES 8
#define DDIM 512
#define ROWSTRIDE 4096 // P*D

__device__ __forceinline__ void glds16(const void* g, void* l) {
  __builtin_amdgcn_global_load_lds((const AS1 uint32_t*)g, (AS3 uint32_t*)l, 16, 0, 0);
}
// pinned-issue global load (compiler may not sink it toward the use)
__device__ __forceinline__ float4 gload4(const float* p) {
  float4 r;
  asm volatile("global_load_dwordx4 %0, %1, off" : "=v"(r) : "v"(p) : "memory");
  return r;
}

__device__ __forceinline__ u16 bf16_rne(float v) {
  union { float f; uint32_t u; } c; c.f = v;
  uint32_t u = c.u + 0x7FFFu + ((c.u >> 16) & 1u);
  return (u16)(u >> 16);
}
__device__ __forceinline__ float bf16_to_f(u16 h) {
  union { uint32_t u; float f; } c; c.u = ((uint32_t)h) << 16;
  return c.f;
}
__device__ __forceinline__ void split2(float v, u16& hi, u16& lo) {
  hi = bf16_rne(v);
  float r = v - bf16_to_f(hi);
  lo = bf16_rne(r);
}

__device__ __forceinline__ void mfma32(const bf16x8 (&A)[8], const bf16x8 (&Bv)[4],
                                       f32x4 (&acc)[8][4]) {
#pragma unroll
  for (int m = 0; m < 8; ++m)
#pragma unroll
    for (int n = 0; n < 4; ++n)
      acc[m][n] = __builtin_amdgcn_mfma_f32_16x16x32_bf16(A[m], Bv[n], acc[m][n], 0, 0, 0);
}

// ---------------------------------------------------------------------------
// fp32 -> (hi, lo) bf16 split for W1, W2 only (x is split in-kernel)
// ---------------------------------------------------------------------------
__global__ void wsplit_kernel(const float* __restrict__ w1, u16* w1hi, u16* w1lo,
                              const float* __restrict__ w2, u16* w2hi, u16* w2lo,
                              int nw) {
  int i = (blockIdx.x * blockDim.x + threadIdx.x) * 4;
  const int stride = gridDim.x * blockDim.x * 4;
  for (; i < nw * 2; i += stride) {
    const float* src; u16 *h, *l; int off;
    if (i < nw) { src = w1; h = w1hi; l = w1lo; off = i; }
    else        { src = w2; h = w2hi; l = w2lo; off = i - nw; }
    float4 v = *reinterpret_cast<const float4*>(src + off);
    ushort4 hh, ll;
    split2(v.x, hh.x, ll.x); split2(v.y, hh.y, ll.y);
    split2(v.z, hh.z, ll.z); split2(v.w, hh.w, ll.w);
    *reinterpret_cast<ushort4*>(h + off) = hh;
    *reinterpret_cast<ushort4*>(l + off) = ll;
  }
}

// ---------------------------------------------------------------------------
// Term-phased split-bf16 GEMM.  C[m,p,n] = sum_d A[m,p,d] * W[p,n,d] (+epi)
// AFP32: A comes from fp32 x (reg-load + in-register split + swizzled
// ds_write); else A planes staged via global_load_lds like B.
// LDS planes: 0=Ahi 1=Alo 2=Bhi 3=Blo, [256][32] bf16, 16B-chunk XOR swizzle
// chunk' = chunk ^ ((row>>1)&3) (reads are full-coverage -> conflict-free).
// EPI==1: gelu(acc+bias) -> split-store OutHi/OutLo.  EPI==2: +bias+resid.
// ---------------------------------------------------------------------------
template <int EPI, bool AFP32>
__global__ __launch_bounds__(512, 2) void gemm_ph(
    const float* __restrict__ Axf,
    const u16* __restrict__ Ahi, const u16* __restrict__ Alo,
    const u16* __restrict__ Bhi, const u16* __restrict__ Blo,
    const float* __restrict__ bias,   // [P][512]
    const float* __restrict__ resid,  // [m][p][d]  (EPI==2)
    u16* __restrict__ OutHi, u16* __restrict__ OutLo,  // EPI==1
    float* __restrict__ OutF)         // EPI==2
{
  // XCD-aware bijective swizzle (256 blocks % 8 == 0): each XCD owns 1 patch
  const int nwg = gridDim.x;
  const int bid = blockIdx.x;
  const int swz = (bid & 7) * (nwg >> 3) + (bid >> 3);
  const int nt = swz & 1;          // 2 col tiles of 256 over N=512
  const int mt = (swz >> 1) & 15;  // 16 row tiles of 256 over M=4096
  const int p  = swz >> 5;         // 8 patches

  __shared__ __attribute__((aligned(16))) u16 sm[2][4][256 * 32];

  const int t    = threadIdx.x;
  const int lane = t & 63;
  const int wv   = t >> 6;
  const int wr   = wv >> 2;        // wave row 0..1 -> m base wr*128
  const int wc   = wv & 3;         // wave col 0..3 -> n base wc*64
  const int fr   = lane & 15;
  const int cS   = (lane >> 4) ^ ((fr >> 1) & 3);   // swizzled chunk (frag reads)

  // glds staging geometry (16B chunks, rows sr0 and sr0+128)
  const int sr0 = t >> 2;
  const int scS = (t & 3) ^ ((sr0 >> 1) & 3);
  const int se0 = t * 8, se1 = se0 + 4096;
  const size_t bG0 = ((size_t)p * DDIM + nt * 256 + sr0) * DDIM + scS * 8;
  const size_t bG1 = bG0 + (size_t)128 * DDIM;
  const size_t aG0 = (size_t)(mt * 256 + sr0) * ROWSTRIDE + (size_t)p * DDIM + scS * 8;
  const size_t aG1 = aG0 + (size_t)128 * ROWSTRIDE;

  // x reg-staging geometry (AFP32): thread owns rows xr, xr+128, cols xc..xc+7
  const int xr  = t >> 2;
  const int xc  = (t & 3) * 8;
  const int xch = (t & 3) ^ ((xr >> 1) & 3);        // same for xr+128
  const int xo0 = xr * 32 + xch * 8;
  const int xo1 = (xr + 128) * 32 + xch * 8;
  const float* xbase = AFP32
      ? (Axf + (size_t)(mt * 256 + xr) * ROWSTRIDE + (size_t)p * DDIM + xc)
      : nullptr;

  f32x4 acc[8][4] = {};
  bf16x8 ah[8], bh[4];
  float4 xv0, xv1, xv2, xv3;

#define DS_A(pl, m) (*(const bf16x8*)&sm[cur][pl][(wr * 128 + (m) * 16 + fr) * 32 + cS * 8])
#define DS_B(pl, n) (*(const bf16x8*)&sm[cur][pl][(wc * 64  + (n) * 16 + fr) * 32 + cS * 8])
#define SPLIT_WRITE(BUF) do {                                                  \
    union { u16 u[8]; bf16x8 v; } H0, L0, H1, L1;                              \
    _Pragma("unroll")                                                          \
    for (int q = 0; q < 4; ++q) {                                              \
      split2(((const float*)&xv0)[q], H0.u[q],     L0.u[q]);                   \
      split2(((const float*)&xv1)[q], H0.u[q + 4], L0.u[q + 4]);               \
      split2(((const float*)&xv2)[q], H1.u[q],     L1.u[q]);                   \
      split2(((const float*)&xv3)[q], H1.u[q + 4], L1.u[q + 4]);               \
    }                                                                          \
    *(bf16x8*)&sm[BUF][0][xo0] = H0.v;  *(bf16x8*)&sm[BUF][1][xo0] = L0.v;     \
    *(bf16x8*)&sm[BUF][0][xo1] = H1.v;  *(bf16x8*)&sm[BUF][1][xo1] = L1.v;     \
  } while (0)

  // ---------------- prologue: tile 0 into buf 0 (one-time full drain) -------
  if constexpr (AFP32) {
    xv0 = gload4(xbase);
    xv1 = gload4(xbase + 4);
    xv2 = gload4(xbase + (size_t)128 * ROWSTRIDE);
    xv3 = gload4(xbase + (size_t)128 * ROWSTRIDE + 4);
    glds16(Bhi + bG0, &sm[0][2][se0]); glds16(Bhi + bG1, &sm[0][2][se1]);
    glds16(Blo + bG0, &sm[0][3][se0]); glds16(Blo + bG1, &sm[0][3][se1]);
    asm volatile("s_waitcnt vmcnt(0)" ::: "memory");
    __builtin_amdgcn_sched_barrier(0);
    SPLIT_WRITE(0);
    asm volatile("s_waitcnt lgkmcnt(0)" ::: "memory");
  } else {
    glds16(Ahi + aG0, &sm[0][0][se0]); glds16(Ahi + aG1, &sm[0][0][se1]);
    glds16(Bhi + bG0, &sm[0][2][se0]); glds16(Bhi + bG1, &sm[0][2][se1]);
    glds16(Blo + bG0, &sm[0][3][se0]); glds16(Blo + bG1, &sm[0][3][se1]);
    glds16(Alo + aG0, &sm[0][1][se0]); glds16(Alo + aG1, &sm[0][1][se1]);
    asm volatile("s_waitcnt vmcnt(0)" ::: "memory");
  }
  __builtin_amdgcn_s_barrier();

  // ---------------- steady loop: tiles 0..14, prefetch t+1 -----------------
  for (int kt = 0; kt < 15; ++kt) {
    const int cur = kt & 1, nxt = cur ^ 1;
    const size_t ko = (size_t)(kt + 1) * 32;

    // ---- phase A : acc += Ahi*Bhi ; issue {x|Ahi}_{t+1}, Bhi_{t+1} ----
#pragma unroll
    for (int n = 0; n < 4; ++n) bh[n] = DS_B(2, n);
#pragma unroll
    for (int m = 0; m < 8; ++m) ah[m] = DS_A(0, m);
    if constexpr (AFP32) {
      xv0 = gload4(xbase + ko);
      xv1 = gload4(xbase + ko + 4);
      xv2 = gload4(xbase + ko + (size_t)128 * ROWSTRIDE);
      xv3 = gload4(xbase + ko + (size_t)128 * ROWSTRIDE + 4);
    } else {
      glds16(Ahi + aG0 + ko, &sm[nxt][0][se0]); glds16(Ahi + aG1 + ko, &sm[nxt][0][se1]);
    }
    glds16(Bhi + bG0 + ko, &sm[nxt][2][se0]); glds16(Bhi + bG1 + ko, &sm[nxt][2][se1]);
    __builtin_amdgcn_s_barrier();
    asm volatile("s_waitcnt lgkmcnt(0)" ::: "memory");
    __builtin_amdgcn_s_setprio(1);
    mfma32(ah, bh, acc);
    __builtin_amdgcn_s_setprio(0);
    asm volatile("s_waitcnt vmcnt(6)" ::: "memory");   // Blo_t landed
    __builtin_amdgcn_s_barrier();

    // ---- phase B : acc += Ahi*Blo ; issue Blo_{t+1} ----
    {
      bf16x8 bl[4];
#pragma unroll
      for (int n = 0; n < 4; ++n) bl[n] = DS_B(3, n);
      glds16(Blo + bG0 + ko, &sm[nxt][3][se0]); glds16(Blo + bG1 + ko, &sm[nxt][3][se1]);
      __builtin_amdgcn_s_barrier();
      asm volatile("s_waitcnt lgkmcnt(0)" ::: "memory");
      __builtin_amdgcn_s_setprio(1);
      mfma32(ah, bl, acc);
      __builtin_amdgcn_s_setprio(0);
      if constexpr (!AFP32)
        asm volatile("s_waitcnt vmcnt(6)" ::: "memory");  // Alo_t landed
      __builtin_amdgcn_s_barrier();
    }

    // ---- phase C : acc += Alo*Bhi ; write A_{t+1} planes / issue Alo_{t+1} ----
    {
      bf16x8 al[8];
#pragma unroll
      for (int m = 0; m < 8; ++m) al[m] = DS_A(1, m);
      if constexpr (!AFP32) {
        glds16(Alo + aG0 + ko, &sm[nxt][1][se0]); glds16(Alo + aG1 + ko, &sm[nxt][1][se1]);
      }
      __builtin_amdgcn_s_barrier();
      asm volatile("s_waitcnt lgkmcnt(0)" ::: "memory");
      __builtin_amdgcn_s_setprio(1);
      mfma32(al, bh, acc);
      __builtin_amdgcn_s_setprio(0);
      if constexpr (AFP32) {
        asm volatile("s_waitcnt vmcnt(4)" ::: "memory");  // x_{t+1} landed
        __builtin_amdgcn_sched_barrier(0);                // rule 18: pin consumers
        SPLIT_WRITE(nxt);
        asm volatile("s_waitcnt vmcnt(2) lgkmcnt(0)" ::: "memory"); // Bhi_{t+1} + my writes
      } else {
        asm volatile("s_waitcnt vmcnt(4)" ::: "memory");  // Ahi,Bhi_{t+1} landed
      }
      __builtin_amdgcn_s_barrier();
    }
  }

  // ---------------- tail: tile 15 (no prefetch) -----------------------------
  {
    const int cur = 1;
#pragma unroll
    for (int n = 0; n < 4; ++n) bh[n] = DS_B(2, n);
#pragma unroll
    for (int m = 0; m < 8; ++m) ah[m] = DS_A(0, m);
    __builtin_amdgcn_s_barrier();
    asm volatile("s_waitcnt lgkmcnt(0)" ::: "memory");
    __builtin_amdgcn_s_setprio(1);
    mfma32(ah, bh, acc);
    __builtin_amdgcn_s_setprio(0);
    if constexpr (AFP32) asm volatile("s_waitcnt vmcnt(0)" ::: "memory");
    else                 asm volatile("s_waitcnt vmcnt(2)" ::: "memory");
    __builtin_amdgcn_s_barrier();
    {
      bf16x8 bl[4];
#pragma unroll
      for (int n = 0; n < 4; ++n) bl[n] = DS_B(3, n);
      __builtin_amdgcn_s_barrier();
      asm volatile("s_waitcnt lgkmcnt(0)" ::: "memory");
      __builtin_amdgcn_s_setprio(1);
      mfma32(ah, bl, acc);
      __builtin_amdgcn_s_setprio(0);
      if constexpr (!AFP32) asm volatile("s_waitcnt vmcnt(0)" ::: "memory");
      __builtin_amdgcn_s_barrier();
    }
    {
      bf16x8 al[8];
#pragma unroll
      for (int m = 0; m < 8; ++m) al[m] = DS_A(1, m);
      __builtin_amdgcn_s_barrier();
      asm volatile("s_waitcnt lgkmcnt(0)" ::: "memory");
      __builtin_amdgcn_s_setprio(1);
      mfma32(al, bh, acc);
      __builtin_amdgcn_s_setprio(0);
    }
  }
#undef DS_A
#undef DS_B
#undef SPLIT_WRITE

  // ---------------- epilogue (C/D layout m89-verified) ----------------------
  const int rquad = (lane >> 4) * 4;
#pragma unroll
  for (int j = 0; j < 4; ++j) {
    const int col = nt * 256 + wc * 64 + j * 16 + fr;
    const float bj = bias[p * DDIM + col];
#pragma unroll
    for (int i = 0; i < 8; ++i) {
      const int row = mt * 256 + wr * 128 + i * 16 + rquad;
#pragma unroll
      for (int r = 0; r < 4; ++r) {
        const size_t idx = (size_t)(row + r) * ROWSTRIDE + (size_t)p * DDIM + col;
        float o = acc[i][j][r] + bj;
        if constexpr (EPI == 1) {
          o = 0.5f * o * (1.0f + erff(o * 0.70710678118654752f));  // exact GELU
          u16 h_, l_;
          split2(o, h_, l_);
          OutHi[idx] = h_;
          OutLo[idx] = l_;
        } else {
          OutF[idx] = o + resid[idx];
        }
      }
    }
  }
}

// ---------------------------------------------------------------------------
extern "C" void kernel_launch(void* const* d_in, const int* in_sizes, int n_in,
                              void* d_out, int out_size, void* d_ws, size_t ws_size,
                              hipStream_t stream) {
  const float* x  = (const float*)d_in[0];
  const float* W1 = (const float*)d_in[1];
  const float* b1 = (const float*)d_in[2];
  const float* W2 = (const float*)d_in[3];
  const float* b2 = (const float*)d_in[4];
  float* out = (float*)d_out;

  const int NX = MTOT * PATCHES * DDIM;   // 16,777,216
  const int NW = PATCHES * DDIM * DDIM;   // 2,097,152

  u16* ws   = (u16*)d_ws;
  u16* w1hi = ws;              // NW each
  u16* w1lo = w1hi + NW;
  u16* w2hi = w1lo + NW;
  u16* w2lo = w2hi + NW;
  u16* hhi  = w2lo + NW;       // NX each
  u16* hlo  = hhi + NX;        // total 84 MB

  wsplit_kernel<<<1024, 256, 0, stream>>>(W1, w1hi, w1lo, W2, w2hi, w2lo, NW);

  gemm_ph<1, true ><<<256, 512, 0, stream>>>(x, nullptr, nullptr, w1hi, w1lo,
                                             b1, nullptr, hhi, hlo, nullptr);
  gemm_ph<2, false><<<256, 512, 0, stream>>>(nullptr, hhi, hlo, w2hi, w2lo,
                                             b2, x, nullptr, nullptr, out);
}